// Round 3
// baseline (227.477 us; speedup 1.0000x reference)
//
#include <hip/hip_runtime.h>

#define BB 2
#define HH 16
#define SS 2048
#define DD 64

constexpr int OSIZE = BB * HH * SS * DD;  // 4,194,304
constexpr float LOG2E = 1.4426950408889634f;

using bf16x8 = __attribute__((ext_vector_type(8))) short;
using f32x4  = __attribute__((ext_vector_type(4))) float;
using u16x8  = __attribute__((ext_vector_type(8))) unsigned short;
using u16x4  = __attribute__((ext_vector_type(4))) unsigned short;
using fl4    = __attribute__((ext_vector_type(4))) float;

__device__ __forceinline__ unsigned short f2bf(float f) {
    unsigned int u = __float_as_uint(f);
    return (unsigned short)((u + 0x7fffu + ((u >> 16) & 1u)) >> 16);
}

__device__ __forceinline__ void atomicMaxPosF(float* addr, float v) {
    atomicMax(reinterpret_cast<unsigned int*>(addr), __float_as_uint(v));
}

// async global->LDS DMA, 16B per lane; lds dest must be wave-uniform base (+lane*16 by HW)
__device__ __forceinline__ void async16(const unsigned short* g, unsigned short* l) {
    __builtin_amdgcn_global_load_lds((const __attribute__((address_space(1))) void*)g,
                                     (__attribute__((address_space(3))) void*)l, 16, 0, 0);
}

// ---- fused prepass: amax init + K->bf16 convert + V->bf16 transpose ----
__global__ __launch_bounds__(256) void prep_kv_kernel(
    const float* __restrict__ k, const float* __restrict__ v,
    const float* __restrict__ dsk, const float* __restrict__ dsv,
    unsigned short* __restrict__ kbf, unsigned short* __restrict__ vtb,
    float* __restrict__ out)
{
    const int t  = threadIdx.x;
    const int s0 = blockIdx.x * 64;
    const int bh = blockIdx.y;
    if (blockIdx.x == 0 && bh == 0 && t < 2) out[OSIZE + t] = 0.0f;

    const size_t base = (size_t)bh * SS * DD;
    const float sck = dsk[0], scv = dsv[0];

    // K convert: 64x64 chunk, 16 contiguous elems/thread
    {
        const float* kp = k + base + (size_t)s0 * DD + t * 16;
        unsigned short* ko = kbf + base + (size_t)s0 * DD + t * 16;
        fl4 a0 = ((const fl4*)kp)[0], a1 = ((const fl4*)kp)[1];
        fl4 a2 = ((const fl4*)kp)[2], a3 = ((const fl4*)kp)[3];
        u16x8 o0, o1;
        #pragma unroll
        for (int j = 0; j < 4; ++j) {
            o0[j] = f2bf(a0[j] * sck); o0[j + 4] = f2bf(a1[j] * sck);
            o1[j] = f2bf(a2[j] * sck); o1[j + 4] = f2bf(a3[j] * sck);
        }
        ((u16x8*)ko)[0] = o0; ((u16x8*)ko)[1] = o1;
    }

    // V transpose via LDS: [s][d] -> [d][s]
    __shared__ unsigned short T[64 * 72];
    {
        const int r  = t >> 2;
        const int cb = (t & 3) * 16;
        const fl4* vp = (const fl4*)(v + base + (size_t)(s0 + r) * DD + cb);
        unsigned short tmp[16];
        #pragma unroll
        for (int c = 0; c < 4; ++c) {
            fl4 x = vp[c];
            #pragma unroll
            for (int j = 0; j < 4; ++j) tmp[c * 4 + j] = f2bf(x[j] * scv);
        }
        *(u16x8*)&T[r * 72 + cb]     = *(u16x8*)&tmp[0];
        *(u16x8*)&T[r * 72 + cb + 8] = *(u16x8*)&tmp[8];
    }
    __syncthreads();
    {
        const int dr = t >> 2;
        const int sb = (t & 3) * 16;
        unsigned short tmp[16];
        #pragma unroll
        for (int j = 0; j < 16; ++j) tmp[j] = T[(sb + j) * 72 + dr];
        unsigned short* op = vtb + base + (size_t)dr * SS + s0 + sb;
        *(u16x8*)op       = *(u16x8*)&tmp[0];
        *(u16x8*)(op + 8) = *(u16x8*)&tmp[8];
    }
}

// ---- main flash-attention kernel: async dbuf staging, XOR-swizzled LDS ----
__global__ __launch_bounds__(256) void fattn_kernel(
    const float* __restrict__ q,
    const unsigned short* __restrict__ kbf,     // bf16 K  [bh][s][d], dsk folded
    const unsigned short* __restrict__ vtb,     // bf16 V^T [bh][d][s], dsv folded
    const float* __restrict__ dsq, const float* __restrict__ qss,
    const float* __restrict__ qso, const float* __restrict__ dss,
    float* __restrict__ out)
{
    const int xr = blockIdx.x;
    const int qt = (xr & 1) ? (31 - (xr >> 1)) : (xr >> 1);
    const int bh = blockIdx.y;
    const int tid  = threadIdx.x;
    const int wave = tid >> 6;
    const int lane = tid & 63;
    const int m16  = lane & 15;
    const int quad = lane >> 4;
    const int m7   = m16 & 7;

    // LDS: K dbuf 2x8KB + V dbuf 2x8KB + P 4x2KB = 40960 B (4 blocks/CU)
    __shared__ __align__(16) unsigned short Ksh[2][64 * 64];
    __shared__ __align__(16) unsigned short Vsh[2][64 * 64];
    __shared__ __align__(16) unsigned short Psh[4][16 * 64];

    const float q_scale = dsq[0] * 0.125f * LOG2E;
    const size_t base = (size_t)bh * SS * DD;
    const unsigned short* kbh = kbf + base;
    const unsigned short* vbh = vtb + base;
    const int qb = qt * 64;

    // staging lane offsets: lane stages LDS granule slot; source granule is XOR-swizzled
    const int slot0 = wave * 64 + lane;        // pass 0: granules [wave*64, +64)
    const int slot1 = (4 + wave) * 64 + lane;  // pass 1
    const int kr0 = slot0 >> 3, kc0 = ((slot0 & 7) ^ (kr0 & 7)) * 8;
    const int kr1 = slot1 >> 3, kc1 = ((slot1 & 7) ^ (kr1 & 7)) * 8;
    const int koff0 = kr0 * DD + kc0, koff1 = kr1 * DD + kc1;
    const int voff0 = kr0 * SS + kc0, voff1 = kr1 * SS + kc1;

    // Q fragment (B operand), prescaled, log2e folded
    bf16x8 qf[2];
    {
        const int qrow = qb + wave * 16 + m16;
        const float* qp = q + base + (size_t)qrow * DD + quad * 8;
        #pragma unroll
        for (int f = 0; f < 2; ++f) {
            fl4 a = *(const fl4*)(qp + f * 32);
            fl4 b = *(const fl4*)(qp + f * 32 + 4);
            #pragma unroll
            for (int j = 0; j < 4; ++j) {
                qf[f][j]     = (short)f2bf(a[j] * q_scale);
                qf[f][j + 4] = (short)f2bf(b[j] * q_scale);
            }
        }
    }

    f32x4 Oacc[4];
    #pragma unroll
    for (int dt = 0; dt < 4; ++dt)
        #pragma unroll
        for (int r = 0; r < 4; ++r) Oacc[dt][r] = 0.0f;

    float m_i = -3.0e38f, l_i = 0.0f;

    const int gsw0 = (quad ^ m7) * 8;          // swizzled granule offsets for frag reads
    const int gsw1 = ((4 | quad) ^ m7) * 8;

    const int nkt = qt + 1;

    // prologue: stage tile 0 into buffer 0
    {
        const unsigned short* kg = kbh;
        const unsigned short* vg = vbh;
        async16(kg + koff0, &Ksh[0][0] + wave * 512);
        async16(kg + koff1, &Ksh[0][0] + 2048 + wave * 512);
        async16(vg + voff0, &Vsh[0][0] + wave * 512);
        async16(vg + voff1, &Vsh[0][0] + 2048 + wave * 512);
    }

    for (int t = 0; t < nkt; ++t) {
        const int b = t & 1;
        __syncthreads();   // vmcnt(0) drain: tile t data landed; buf b^1 readers done

        if (t + 1 < nkt) {  // prefetch tile t+1 into the other buffer (flies during compute)
            const unsigned short* kg = kbh + (t + 1) * 64 * DD;
            const unsigned short* vg = vbh + (t + 1) * 64;
            async16(kg + koff0, &Ksh[b ^ 1][0] + wave * 512);
            async16(kg + koff1, &Ksh[b ^ 1][0] + 2048 + wave * 512);
            async16(vg + voff0, &Vsh[b ^ 1][0] + wave * 512);
            async16(vg + voff1, &Vsh[b ^ 1][0] + 2048 + wave * 512);
        }

        const unsigned short* Kt = &Ksh[b][0];
        const unsigned short* Vt = &Vsh[b][0];

        // S^T = K Q^T : C[row=k=quad*4+r][col=q=m16]
        f32x4 sacc[4];
        #pragma unroll
        for (int nt = 0; nt < 4; ++nt) {
            f32x4 acc = {0.0f, 0.0f, 0.0f, 0.0f};
            const int rb = (nt * 16 + m16) * 64;
            bf16x8 kf0 = *(const bf16x8*)&Kt[rb + gsw0];
            bf16x8 kf1 = *(const bf16x8*)&Kt[rb + gsw1];
            acc = __builtin_amdgcn_mfma_f32_16x16x32_bf16(kf0, qf[0], acc, 0, 0, 0);
            acc = __builtin_amdgcn_mfma_f32_16x16x32_bf16(kf1, qf[1], acc, 0, 0, 0);
            sacc[nt] = acc;
        }

        if (t == nkt - 1) {  // causal mask on diagonal tile
            const int qg = qb + wave * 16 + m16;
            const int kb = t * 64;
            #pragma unroll
            for (int nt = 0; nt < 4; ++nt)
                #pragma unroll
                for (int r = 0; r < 4; ++r) {
                    const int kc = kb + nt * 16 + quad * 4 + r;
                    if (kc > qg) sacc[nt][r] = -1.0e30f;
                }
        }

        // online softmax (row q = m16, reduce across quads)
        float mx = -3.0e38f;
        #pragma unroll
        for (int nt = 0; nt < 4; ++nt)
            #pragma unroll
            for (int r = 0; r < 4; ++r) mx = fmaxf(mx, sacc[nt][r]);
        mx = fmaxf(mx, __shfl_xor(mx, 16));
        mx = fmaxf(mx, __shfl_xor(mx, 32));
        const float mn = fmaxf(m_i, mx);
        const float alpha = __builtin_amdgcn_exp2f(m_i - mn);
        m_i = mn;

        float rs = 0.0f;
        #pragma unroll
        for (int nt = 0; nt < 4; ++nt)
            #pragma unroll
            for (int r = 0; r < 4; ++r) {
                const float p = __builtin_amdgcn_exp2f(sacc[nt][r] - mn);
                sacc[nt][r] = p;
                rs += p;
            }
        rs += __shfl_xor(rs, 16);
        rs += __shfl_xor(rs, 32);
        l_i = l_i * alpha + rs;

        // rescale O (O rows are q = quad*4+r)
        #pragma unroll
        for (int r = 0; r < 4; ++r) {
            const float af = __shfl(alpha, (lane & 48) | (quad * 4 + r));
            #pragma unroll
            for (int dt = 0; dt < 4; ++dt) Oacc[dt][r] *= af;
        }

        // P: C-layout -> A-layout via swizzled per-wave LDS (wave-internal, no barrier)
        unsigned short* P = &Psh[wave][0];
        #pragma unroll
        for (int nt = 0; nt < 4; ++nt) {
            u16x4 pk;
            #pragma unroll
            for (int r = 0; r < 4; ++r) pk[r] = f2bf(sacc[nt][r]);
            const int g = nt * 2 + (quad >> 1);
            *(u16x4*)&P[m16 * 64 + ((g ^ m7) * 8) + (quad & 1) * 4] = pk;
        }
        bf16x8 pf0 = *(const bf16x8*)&P[m16 * 64 + gsw0];
        bf16x8 pf1 = *(const bf16x8*)&P[m16 * 64 + gsw1];

        // O += P V
        #pragma unroll
        for (int dt = 0; dt < 4; ++dt) {
            const int rb = (dt * 16 + m16) * 64;
            bf16x8 vf0 = *(const bf16x8*)&Vt[rb + gsw0];
            bf16x8 vf1 = *(const bf16x8*)&Vt[rb + gsw1];
            Oacc[dt] = __builtin_amdgcn_mfma_f32_16x16x32_bf16(pf0, vf0, Oacc[dt], 0, 0, 0);
            Oacc[dt] = __builtin_amdgcn_mfma_f32_16x16x32_bf16(pf1, vf1, Oacc[dt], 0, 0, 0);
        }
    }

    // epilogue
    const float ss_ = qss[0] * dss[0];
    const float o_q = qso[0];
    float amax_o = 0.0f;
    #pragma unroll
    for (int r = 0; r < 4; ++r) {
        const float lr  = __shfl(l_i, (lane & 48) | (quad * 4 + r));
        const float ivl = ss_ / lr;
        const int row = qb + wave * 16 + quad * 4 + r;
        float* op = out + base + (size_t)row * DD + m16;
        #pragma unroll
        for (int dt = 0; dt < 4; ++dt) {
            const float o_raw = Oacc[dt][r] * ivl;
            amax_o = fmaxf(amax_o, fabsf(o_raw));
            op[dt * 16] = o_raw * o_q;
        }
    }
    float amax_s = 1.0f / l_i;
    #pragma unroll
    for (int m = 1; m < 64; m <<= 1) {
        amax_o = fmaxf(amax_o, __shfl_xor(amax_o, m));
        amax_s = fmaxf(amax_s, __shfl_xor(amax_s, m));
    }
    if (lane == 0) {
        atomicMaxPosF(out + OSIZE,     amax_s);
        atomicMaxPosF(out + OSIZE + 1, amax_o);
    }
}

extern "C" void kernel_launch(void* const* d_in, const int* in_sizes, int n_in,
                              void* d_out, int out_size, void* d_ws, size_t ws_size,
                              hipStream_t stream) {
    const float* q   = (const float*)d_in[0];
    const float* k   = (const float*)d_in[1];
    const float* v   = (const float*)d_in[2];
    const float* dsq = (const float*)d_in[3];
    const float* dsk = (const float*)d_in[4];
    const float* dsv = (const float*)d_in[5];
    const float* qss = (const float*)d_in[6];
    const float* qso = (const float*)d_in[7];
    const float* dss = (const float*)d_in[8];
    float* out = (float*)d_out;

    unsigned short* kbf = (unsigned short*)d_ws;            // 8 MB
    unsigned short* vtb = (unsigned short*)d_ws + OSIZE;    // 8 MB

    prep_kv_kernel<<<dim3(SS / 64, BB * HH), 256, 0, stream>>>(k, v, dsk, dsv, kbf, vtb, out);

    dim3 grid(SS / 64, BB * HH);   // (32, 32), qt remapped inside
    fattn_kernel<<<grid, 256, 0, stream>>>(q, kbf, vtb, dsq, qss, qso, dss, out);
}

// Round 4
// 221.429 us; speedup vs baseline: 1.0273x; 1.0273x over previous
//
#include <hip/hip_runtime.h>

#define BB 2
#define HH 16
#define SS 2048
#define DD 64

constexpr int OSIZE = BB * HH * SS * DD;  // 4,194,304
constexpr float LOG2E = 1.4426950408889634f;

using bf16x8 = __attribute__((ext_vector_type(8))) short;
using f32x4  = __attribute__((ext_vector_type(4))) float;
using u16x8  = __attribute__((ext_vector_type(8))) unsigned short;
using u16x4  = __attribute__((ext_vector_type(4))) unsigned short;
using fl4    = __attribute__((ext_vector_type(4))) float;

__device__ __forceinline__ unsigned short f2bf(float f) {
    unsigned int u = __float_as_uint(f);
    return (unsigned short)((u + 0x7fffu + ((u >> 16) & 1u)) >> 16);
}

__device__ __forceinline__ void atomicMaxPosF(float* addr, float v) {
    atomicMax(reinterpret_cast<unsigned int*>(addr), __float_as_uint(v));
}

// ---- fused prepass: amax init + K->bf16 convert + V->bf16 transpose ----
__global__ __launch_bounds__(256) void prep_kv_kernel(
    const float* __restrict__ k, const float* __restrict__ v,
    const float* __restrict__ dsk, const float* __restrict__ dsv,
    unsigned short* __restrict__ kbf, unsigned short* __restrict__ vtb,
    float* __restrict__ out)
{
    const int t  = threadIdx.x;
    const int s0 = blockIdx.x * 64;
    const int bh = blockIdx.y;
    if (blockIdx.x == 0 && bh == 0 && t < 2) out[OSIZE + t] = 0.0f;

    const size_t base = (size_t)bh * SS * DD;
    const float sck = dsk[0], scv = dsv[0];

    // K convert: 64x64 chunk, 16 contiguous elems/thread
    {
        const float* kp = k + base + (size_t)s0 * DD + t * 16;
        unsigned short* ko = kbf + base + (size_t)s0 * DD + t * 16;
        fl4 a0 = ((const fl4*)kp)[0], a1 = ((const fl4*)kp)[1];
        fl4 a2 = ((const fl4*)kp)[2], a3 = ((const fl4*)kp)[3];
        u16x8 o0, o1;
        #pragma unroll
        for (int j = 0; j < 4; ++j) {
            o0[j] = f2bf(a0[j] * sck); o0[j + 4] = f2bf(a1[j] * sck);
            o1[j] = f2bf(a2[j] * sck); o1[j + 4] = f2bf(a3[j] * sck);
        }
        ((u16x8*)ko)[0] = o0; ((u16x8*)ko)[1] = o1;
    }

    // V transpose via LDS: [s][d] -> [d][s]
    __shared__ unsigned short T[64 * 72];
    {
        const int r  = t >> 2;
        const int cb = (t & 3) * 16;
        const fl4* vp = (const fl4*)(v + base + (size_t)(s0 + r) * DD + cb);
        unsigned short tmp[16];
        #pragma unroll
        for (int c = 0; c < 4; ++c) {
            fl4 x = vp[c];
            #pragma unroll
            for (int j = 0; j < 4; ++j) tmp[c * 4 + j] = f2bf(x[j] * scv);
        }
        *(u16x8*)&T[r * 72 + cb]     = *(u16x8*)&tmp[0];
        *(u16x8*)&T[r * 72 + cb + 8] = *(u16x8*)&tmp[8];
    }
    __syncthreads();
    {
        const int dr = t >> 2;
        const int sb = (t & 3) * 16;
        unsigned short tmp[16];
        #pragma unroll
        for (int j = 0; j < 16; ++j) tmp[j] = T[(sb + j) * 72 + dr];
        unsigned short* op = vtb + base + (size_t)dr * SS + s0 + sb;
        *(u16x8*)op       = *(u16x8*)&tmp[0];
        *(u16x8*)(op + 8) = *(u16x8*)&tmp[8];
    }
}

// ---- main kernel: barrier-free, register-direct K/V fragments, 2 q-strips/wave ----
__global__ __launch_bounds__(256, 2) void fattn_kernel(
    const float* __restrict__ q,
    const unsigned short* __restrict__ kbf,     // bf16 K  [bh][s][d], dsk folded
    const unsigned short* __restrict__ vtb,     // bf16 V^T [bh][d][s], dsv folded
    const float* __restrict__ dsq, const float* __restrict__ qss,
    const float* __restrict__ qso, const float* __restrict__ dss,
    float* __restrict__ out)
{
    const int xr = blockIdx.x;                       // 0..15
    const int qt = (xr & 1) ? (15 - (xr >> 1)) : (xr >> 1);   // balanced interleave
    const int bh = blockIdx.y;
    const int tid  = threadIdx.x;
    const int wave = tid >> 6;
    const int lane = tid & 63;
    const int m16  = lane & 15;
    const int quad = lane >> 4;
    const int m7   = m16 & 7;

    // LDS: per-wave per-strip P scratch only (no barriers anywhere)
    __shared__ __align__(16) unsigned short Psh[4][2][16 * 64];

    const float q_scale = dsq[0] * 0.125f * LOG2E;
    const size_t base = (size_t)bh * SS * DD;
    const int qb = qt * 128;

    // Q fragments (B operand), 2 strips, prescaled
    bf16x8 qf[2][2];
    #pragma unroll
    for (int s = 0; s < 2; ++s) {
        const int qrow = qb + wave * 32 + s * 16 + m16;
        const float* qp = q + base + (size_t)qrow * DD + quad * 8;
        #pragma unroll
        for (int f = 0; f < 2; ++f) {
            fl4 a = *(const fl4*)(qp + f * 32);
            fl4 b = *(const fl4*)(qp + f * 32 + 4);
            #pragma unroll
            for (int j = 0; j < 4; ++j) {
                qf[s][f][j]     = (short)f2bf(a[j] * q_scale);
                qf[s][f][j + 4] = (short)f2bf(b[j] * q_scale);
            }
        }
    }

    f32x4 Oacc[2][4];
    #pragma unroll
    for (int s = 0; s < 2; ++s)
        #pragma unroll
        for (int dt = 0; dt < 4; ++dt)
            #pragma unroll
            for (int r = 0; r < 4; ++r) Oacc[s][dt][r] = 0.0f;

    float m_i[2] = {-3.0e38f, -3.0e38f}, l_i[2] = {0.0f, 0.0f};

    const int gsw0 = (quad ^ m7) * 8;   // swizzled granule offsets (P reads)
    const int gsw1 = ((4 | quad) ^ m7) * 8;

    // fragment base pointers (advance per tile)
    const unsigned short* kp = kbf + base + (size_t)m16 * DD + quad * 8;
    const unsigned short* vp = vtb + base + (size_t)m16 * SS + quad * 8;

    const int nkt = qb / 64 + 1 + (wave >> 1);   // wave-local causal tile count

    for (int t = 0; t < nkt; ++t) {
        const int kb = t * 64;

        // ---- direct global->register fragment loads (L2-resident, 16B/lane) ----
        bf16x8 kf[4][2], vf[4][2];
        #pragma unroll
        for (int nt = 0; nt < 4; ++nt) {
            const unsigned short* kr = kp + (size_t)(kb + nt * 16) * DD;
            kf[nt][0] = *(const bf16x8*)kr;
            kf[nt][1] = *(const bf16x8*)(kr + 32);
        }
        #pragma unroll
        for (int dt = 0; dt < 4; ++dt) {
            const unsigned short* vr = vp + (size_t)(dt * 16) * SS + kb;
            vf[dt][0] = *(const bf16x8*)vr;
            vf[dt][1] = *(const bf16x8*)(vr + 32);
        }

        // ---- S^T = K Q^T for both strips: C[row=k=quad*4+r][col=q=m16] ----
        f32x4 sacc[2][4];
        #pragma unroll
        for (int s = 0; s < 2; ++s)
            #pragma unroll
            for (int nt = 0; nt < 4; ++nt) {
                f32x4 acc = {0.0f, 0.0f, 0.0f, 0.0f};
                acc = __builtin_amdgcn_mfma_f32_16x16x32_bf16(kf[nt][0], qf[s][0], acc, 0, 0, 0);
                acc = __builtin_amdgcn_mfma_f32_16x16x32_bf16(kf[nt][1], qf[s][1], acc, 0, 0, 0);
                sacc[s][nt] = acc;
            }

        // ---- causal mask (both strips share the same diagonal tile index) ----
        if (t == nkt - 1) {
            #pragma unroll
            for (int s = 0; s < 2; ++s) {
                const int qg = qb + wave * 32 + s * 16 + m16;
                #pragma unroll
                for (int nt = 0; nt < 4; ++nt)
                    #pragma unroll
                    for (int r = 0; r < 4; ++r) {
                        const int kc = kb + nt * 16 + quad * 4 + r;
                        if (kc > qg) sacc[s][nt][r] = -1.0e30f;
                    }
            }
        }

        // ---- per-strip: online softmax + P repack + PV ----
        #pragma unroll
        for (int s = 0; s < 2; ++s) {
            float mx = -3.0e38f;
            #pragma unroll
            for (int nt = 0; nt < 4; ++nt)
                #pragma unroll
                for (int r = 0; r < 4; ++r) mx = fmaxf(mx, sacc[s][nt][r]);
            mx = fmaxf(mx, __shfl_xor(mx, 16));
            mx = fmaxf(mx, __shfl_xor(mx, 32));
            const float mn = fmaxf(m_i[s], mx);
            const float alpha = __builtin_amdgcn_exp2f(m_i[s] - mn);
            m_i[s] = mn;

            float rs = 0.0f;
            #pragma unroll
            for (int nt = 0; nt < 4; ++nt)
                #pragma unroll
                for (int r = 0; r < 4; ++r) {
                    const float p = __builtin_amdgcn_exp2f(sacc[s][nt][r] - mn);
                    sacc[s][nt][r] = p;
                    rs += p;
                }
            rs += __shfl_xor(rs, 16);
            rs += __shfl_xor(rs, 32);
            l_i[s] = l_i[s] * alpha + rs;

            #pragma unroll
            for (int r = 0; r < 4; ++r) {
                const float af = __shfl(alpha, (lane & 48) | (quad * 4 + r));
                #pragma unroll
                for (int dt = 0; dt < 4; ++dt) Oacc[s][dt][r] *= af;
            }

            // P: C-layout -> A-layout via swizzled per-wave/per-strip LDS (no barrier)
            unsigned short* P = &Psh[wave][s][0];
            #pragma unroll
            for (int nt = 0; nt < 4; ++nt) {
                u16x4 pk;
                #pragma unroll
                for (int r = 0; r < 4; ++r) pk[r] = f2bf(sacc[s][nt][r]);
                const int g = nt * 2 + (quad >> 1);
                *(u16x4*)&P[m16 * 64 + ((g ^ m7) * 8) + (quad & 1) * 4] = pk;
            }
            bf16x8 pf0 = *(const bf16x8*)&P[m16 * 64 + gsw0];
            bf16x8 pf1 = *(const bf16x8*)&P[m16 * 64 + gsw1];

            #pragma unroll
            for (int dt = 0; dt < 4; ++dt) {
                Oacc[s][dt] = __builtin_amdgcn_mfma_f32_16x16x32_bf16(pf0, vf[dt][0], Oacc[s][dt], 0, 0, 0);
                Oacc[s][dt] = __builtin_amdgcn_mfma_f32_16x16x32_bf16(pf1, vf[dt][1], Oacc[s][dt], 0, 0, 0);
            }
        }
    }

    // ---- epilogue ----
    const float ss_ = qss[0] * dss[0];
    const float o_q = qso[0];
    float amax_o = 0.0f, amax_s = 0.0f;
    #pragma unroll
    for (int s = 0; s < 2; ++s) {
        amax_s = fmaxf(amax_s, 1.0f / l_i[s]);
        #pragma unroll
        for (int r = 0; r < 4; ++r) {
            const float lr  = __shfl(l_i[s], (lane & 48) | (quad * 4 + r));
            const float ivl = ss_ / lr;
            const int row = qb + wave * 32 + s * 16 + quad * 4 + r;
            float* op = out + base + (size_t)row * DD + m16;
            #pragma unroll
            for (int dt = 0; dt < 4; ++dt) {
                const float o_raw = Oacc[s][dt][r] * ivl;
                amax_o = fmaxf(amax_o, fabsf(o_raw));
                op[dt * 16] = o_raw * o_q;
            }
        }
    }
    #pragma unroll
    for (int m = 1; m < 64; m <<= 1) {
        amax_o = fmaxf(amax_o, __shfl_xor(amax_o, m));
        amax_s = fmaxf(amax_s, __shfl_xor(amax_s, m));
    }
    if (lane == 0) {
        atomicMaxPosF(out + OSIZE,     amax_s);
        atomicMaxPosF(out + OSIZE + 1, amax_o);
    }
}

extern "C" void kernel_launch(void* const* d_in, const int* in_sizes, int n_in,
                              void* d_out, int out_size, void* d_ws, size_t ws_size,
                              hipStream_t stream) {
    const float* q   = (const float*)d_in[0];
    const float* k   = (const float*)d_in[1];
    const float* v   = (const float*)d_in[2];
    const float* dsq = (const float*)d_in[3];
    const float* dsk = (const float*)d_in[4];
    const float* dsv = (const float*)d_in[5];
    const float* qss = (const float*)d_in[6];
    const float* qso = (const float*)d_in[7];
    const float* dss = (const float*)d_in[8];
    float* out = (float*)d_out;

    unsigned short* kbf = (unsigned short*)d_ws;            // 8 MB
    unsigned short* vtb = (unsigned short*)d_ws + OSIZE;    // 8 MB

    prep_kv_kernel<<<dim3(SS / 64, BB * HH), 256, 0, stream>>>(k, v, dsk, dsv, kbf, vtb, out);

    dim3 grid(SS / 128, BB * HH);   // (16, 32), qt remapped inside
    fattn_kernel<<<grid, 256, 0, stream>>>(q, kbf, vtb, dsq, qss, qso, dss, out);
}